// Round 1
// baseline (730.182 us; speedup 1.0000x reference)
//
#include <hip/hip_runtime.h>
#include <math.h>

#define HH 128
#define WW 128
#define CG 8
#define NN 256
#define HWSZ (HH*WW)

__device__ __forceinline__ float sigmoidf_(float x){ return 1.0f/(1.0f+__expf(-x)); }

__device__ __forceinline__ unsigned short f2bf(float x){
  union { float f; unsigned u; } v; v.f = x;
  unsigned r = v.u + 0x7fffu + ((v.u >> 16) & 1u);
  return (unsigned short)(r >> 16);
}
__device__ __forceinline__ float bf2f(unsigned short h){
  union { unsigned u; float f; } v; v.u = ((unsigned)h) << 16; return v.f;
}

// ---------------- Kernel A: row/col means -> 8x8 fuse conv -> sigmoid ----------
__global__ __launch_bounds__(256) void kA(const float* __restrict__ gx,
                                          const float* __restrict__ afw,
                                          float* __restrict__ sig_h,
                                          float* __restrict__ sig_w){
  int n = blockIdx.x;
  int tid = threadIdx.x;
  __shared__ float xh[CG][HH];
  __shared__ float xw[CG][WW];
  __shared__ float colpart[2][WW];
  const float* base_n = gx + (size_t)n*CG*HWSZ;
  for (int c = 0; c < CG; ++c){
    const float* img = base_n + c*HWSZ;
    // column sums (coalesced)
    int w = tid & 127, rh = tid >> 7;
    float acc = 0.f;
    const float* p = img + rh*64*WW + w;
    for (int h = 0; h < 64; ++h) acc += p[h*WW];
    colpart[rh][w] = acc;
    // row sums (L2-hot second read)
    int h2 = tid >> 1, wh = tid & 1;
    float racc = 0.f;
    const float* rp = img + h2*WW + wh*64;
    for (int j = 0; j < 64; ++j) racc += rp[j];
    racc += __shfl_xor(racc, 1);
    __syncthreads();
    if (tid < WW) xw[c][tid] = (colpart[0][tid] + colpart[1][tid]) * (1.0f/HH);
    if (wh == 0) xh[c][h2] = racc * (1.0f/WW);
    __syncthreads();
  }
  // fuse conv (8x8) + sigmoid.  threads 0..127: h-side; 128..255: w-side
  if (tid < HH){
    int h = tid;
    float v[CG];
    #pragma unroll
    for (int c = 0; c < CG; ++c) v[c] = xh[c][h];
    #pragma unroll
    for (int o = 0; o < CG; ++o){
      float s = 0.f;
      #pragma unroll
      for (int i = 0; i < CG; ++i) s = fmaf(afw[o*CG+i], v[i], s);
      sig_h[(n*CG+o)*HH + h] = sigmoidf_(s);
    }
  } else {
    int w = tid - 128;
    float v[CG];
    #pragma unroll
    for (int c = 0; c < CG; ++c) v[c] = xw[c][w];
    #pragma unroll
    for (int o = 0; o < CG; ++o){
      float s = 0.f;
      #pragma unroll
      for (int i = 0; i < CG; ++i) s = fmaf(afw[o*CG+i], v[i], s);
      sig_w[(n*CG+o)*WW + w] = sigmoidf_(s);
    }
  }
}

// ---------------- Kernel B: GroupNorm stats of t = gx*sigh*sigw ----------------
__global__ __launch_bounds__(256) void kB(const float* __restrict__ gx,
                                          const float* __restrict__ sig_h,
                                          const float* __restrict__ sig_w,
                                          const float* __restrict__ gn_w,
                                          const float* __restrict__ gn_b,
                                          float* __restrict__ Agn,
                                          float* __restrict__ Bgn){
  int b = blockIdx.x; int n = b >> 3; int c = b & 7;
  int tid = threadIdx.x;
  __shared__ float sh[HH];
  __shared__ float swv[WW];
  __shared__ float red[16];
  if (tid < HH) sh[tid] = sig_h[(n*CG+c)*HH + tid];
  else          swv[tid-128] = sig_w[(n*CG+c)*WW + tid - 128];
  __syncthreads();
  const float* img = gx + (size_t)(n*CG+c)*HWSZ;
  float s1 = 0.f, s2 = 0.f;
  for (int idx = tid; idx < HWSZ; idx += 256){
    int h = idx >> 7, w = idx & 127;
    float t = img[idx] * sh[h] * swv[w];
    s1 += t; s2 = fmaf(t, t, s2);
  }
  #pragma unroll
  for (int off = 32; off; off >>= 1){ s1 += __shfl_down(s1, off); s2 += __shfl_down(s2, off); }
  int wv = tid >> 6, ln = tid & 63;
  if (ln == 0){ red[wv] = s1; red[8+wv] = s2; }
  __syncthreads();
  if (tid == 0){
    float S1 = red[0]+red[1]+red[2]+red[3];
    float S2 = red[8]+red[9]+red[10]+red[11];
    float mu  = S1 * (1.0f/HWSZ);
    float var = S2 * (1.0f/HWSZ) - mu*mu;
    float rstd = rsqrtf(var + 1e-5f);
    float A = rstd * gn_w[c];
    Agn[n*CG+c] = A;
    Bgn[n*CG+c] = gn_b[c] - mu*A;
  }
}

// ---------------- Kernel C: fused convs, x1/x2 maps + gate partial sums --------
__global__ __launch_bounds__(256) void kC(const float* __restrict__ gx,
                                          const float* __restrict__ w1,
                                          const float* __restrict__ w3,
                                          const float* __restrict__ w5,
                                          const float* __restrict__ scale_w,
                                          const float* __restrict__ spw,
                                          const float* __restrict__ sig_h,
                                          const float* __restrict__ sig_w,
                                          const float* __restrict__ Agn,
                                          const float* __restrict__ Bgn,
                                          unsigned short* __restrict__ x1m,
                                          unsigned short* __restrict__ x2m,
                                          float* __restrict__ gacc){
  __shared__ __align__(16) float tile[CG][36][36];
  __shared__ float w5L[CG*CG*25];
  __shared__ float w3L[CG*CG*9];
  __shared__ float coefA[CG][CG];
  __shared__ float constA[CG];
  __shared__ float sighs[CG][32];
  __shared__ float sigws[CG][32];
  __shared__ float spwL[CG];
  __shared__ float wred[4][32];

  int tid = threadIdx.x;
  int bb = blockIdx.x;
  int n  = bb >> 4;
  int t_ = bb & 15;
  int y0 = (t_ >> 2) * 32;
  int x0 = (t_ & 3) * 32;

  // softmax(scale_w) (3 values, every thread computes)
  float sw0, sw1, sw2;
  {
    float a = scale_w[0], b = scale_w[1], c = scale_w[2];
    float m = fmaxf(a, fmaxf(b, c));
    float e0 = __expf(a-m), e1 = __expf(b-m), e2 = __expf(c-m);
    float inv = 1.0f/(e0+e1+e2);
    sw0 = e0*inv; sw1 = e1*inv; sw2 = e2*inv;
  }
  for (int i = tid; i < CG*CG*25; i += 256) w5L[i] = sw2 * w5[i];
  for (int i = tid; i < CG*CG*9;  i += 256) w3L[i] = w3[i];
  if (tid < 64){
    int oc = tid >> 3, ic = tid & 7;
    coefA[oc][ic] = sw0 * w1[oc*CG+ic] * Agn[n*CG+ic];
  }
  if (tid < CG){
    float s = 0.f;
    for (int i = 0; i < CG; ++i) s = fmaf(w1[tid*CG+i], Bgn[n*CG+i], s);
    constA[tid] = sw0 * s;
    spwL[tid] = spw[tid];
  }
  {
    int ic = tid >> 5, k = tid & 31;
    sighs[ic][k] = sig_h[(n*CG+ic)*HH + y0 + k];
    sigws[ic][k] = sig_w[(n*CG+ic)*WW + x0 + k];
  }
  const float* base_n = gx + (size_t)n*CG*HWSZ;
  for (int ic = 0; ic < CG; ++ic){
    const float* img = base_n + ic*HWSZ;
    for (int idx = tid; idx < 36*36; idx += 256){
      int yy = idx / 36, xx = idx - yy*36;
      int gy = y0 + yy - 2, gxx = x0 + xx - 2;
      float v = 0.f;
      if (gy >= 0 && gy < HH && gxx >= 0 && gxx < WW) v = img[gy*WW + gxx];
      tile[ic][yy][xx] = v;
    }
  }
  __syncthreads();

  int tc = tid & 7, row = tid >> 3;
  int xl = tc * 4;
  float accA[CG][4];  // sw0*xa + sw2*xc
  float accB[CG][4];  // raw 3x3 (= x2)
  #pragma unroll
  for (int oc = 0; oc < CG; ++oc)
    #pragma unroll
    for (int p = 0; p < 4; ++p){ accA[oc][p] = constA[oc]; accB[oc][p] = 0.f; }

  #pragma unroll 1
  for (int ic = 0; ic < CG; ++ic){
    float shh = sighs[ic][row];
    float sg0 = sigws[ic][xl], sg1 = sigws[ic][xl+1], sg2 = sigws[ic][xl+2], sg3 = sigws[ic][xl+3];
    const float* w5p = &w5L[ic*25];
    const float* w3p = &w3L[ic*9];
    #pragma unroll
    for (int ky = 0; ky < 5; ++ky){
      const float* trow = &tile[ic][row+ky][xl];
      float4 v0 = *reinterpret_cast<const float4*>(trow);
      float4 v1 = *reinterpret_cast<const float4*>(trow + 4);
      float in[8] = {v0.x, v0.y, v0.z, v0.w, v1.x, v1.y, v1.z, v1.w};
      #pragma unroll
      for (int oc = 0; oc < CG; ++oc){
        const float* wrow = w5p + oc*(CG*25) + ky*5;
        #pragma unroll
        for (int kx = 0; kx < 5; ++kx){
          float wv = wrow[kx];
          #pragma unroll
          for (int p = 0; p < 4; ++p) accA[oc][p] = fmaf(wv, in[kx+p], accA[oc][p]);
        }
      }
      if (ky >= 1 && ky <= 3){
        #pragma unroll
        for (int oc = 0; oc < CG; ++oc){
          const float* wrow3 = w3p + oc*(CG*9) + (ky-1)*3;
          #pragma unroll
          for (int kx = 0; kx < 3; ++kx){
            float wv = wrow3[kx];
            #pragma unroll
            for (int p = 0; p < 4; ++p) accB[oc][p] = fmaf(wv, in[kx+p+1], accB[oc][p]);
          }
        }
      }
      if (ky == 2){
        float t0 = in[2]*shh*sg0, t1 = in[3]*shh*sg1, t2 = in[4]*shh*sg2, t3 = in[5]*shh*sg3;
        #pragma unroll
        for (int oc = 0; oc < CG; ++oc){
          float cf = coefA[oc][ic];
          accA[oc][0] = fmaf(cf, t0, accA[oc][0]);
          accA[oc][1] = fmaf(cf, t1, accA[oc][1]);
          accA[oc][2] = fmaf(cf, t2, accA[oc][2]);
          accA[oc][3] = fmaf(cf, t3, accA[oc][3]);
        }
      }
    }
  }

  // epilogue: sp-gates per pixel, bf16 stores, partial sums
  float sp1a[4], sp2a[4];
  #pragma unroll
  for (int p = 0; p < 4; ++p){
    float d1 = 0.f, d2 = 0.f;
    #pragma unroll
    for (int oc = 0; oc < CG; ++oc){
      float xb = accB[oc][p];
      float v1 = accA[oc][p] + sw1*xb;
      d1 = fmaf(spwL[oc], v1, d1);
      d2 = fmaf(spwL[oc], xb, d2);
    }
    sp1a[p] = sigmoidf_(d1); sp2a[p] = sigmoidf_(d2);
  }
  int lane = tid & 63, wv = tid >> 6;
  size_t obase = (size_t)(n*CG)*HWSZ + (size_t)(y0+row)*WW + (x0+xl);
  #pragma unroll
  for (int oc = 0; oc < CG; ++oc){
    float s1 = 0.f, qq1 = 0.f, s2 = 0.f, qq2 = 0.f;
    ushort4 u1, u2;
    #pragma unroll
    for (int p = 0; p < 4; ++p){
      float xb = accB[oc][p];
      float v1 = accA[oc][p] + sw1*xb;
      s1 += v1; s2 += xb;
      qq1 = fmaf(v1, sp1a[p], qq1); qq2 = fmaf(xb, sp2a[p], qq2);
      ((unsigned short*)&u1)[p] = f2bf(v1);
      ((unsigned short*)&u2)[p] = f2bf(xb);
    }
    *reinterpret_cast<ushort4*>(x1m + obase + (size_t)oc*HWSZ) = u1;
    *reinterpret_cast<ushort4*>(x2m + obase + (size_t)oc*HWSZ) = u2;
    #pragma unroll
    for (int off = 32; off; off >>= 1){
      s1 += __shfl_down(s1, off); qq1 += __shfl_down(qq1, off);
      s2 += __shfl_down(s2, off); qq2 += __shfl_down(qq2, off);
    }
    if (lane == 0){ wred[wv][oc] = s1; wred[wv][8+oc] = qq1; wred[wv][16+oc] = s2; wred[wv][24+oc] = qq2; }
  }
  __syncthreads();
  if (tid < 32){
    float s = wred[0][tid] + wred[1][tid] + wred[2][tid] + wred[3][tid];
    atomicAdd(&gacc[n*32 + tid], s);
  }
}

// ---------------- Kernel T: channel gates + softmaxes -> a1,a2 -----------------
__global__ void kT(const float* __restrict__ gacc, const float* __restrict__ cgw,
                   float* __restrict__ a1a2){
  int n = blockIdx.x*blockDim.x + threadIdx.x;
  if (n >= NN) return;
  const float* g = gacc + n*32;
  float m1[CG], q1[CG], m2[CG], q2[CG];
  #pragma unroll
  for (int c = 0; c < CG; ++c){
    m1[c] = g[c]      * (1.0f/HWSZ);
    q1[c] = g[8+c]    * (1.0f/HWSZ);
    m2[c] = g[16+c]   * (1.0f/HWSZ);
    q2[c] = g[24+c]   * (1.0f/HWSZ);
  }
  float chg1[CG], chg2[CG];
  #pragma unroll
  for (int o = 0; o < CG; ++o){
    float s1 = 0.f, s2 = 0.f;
    #pragma unroll
    for (int i = 0; i < CG; ++i){ s1 = fmaf(cgw[o*CG+i], m1[i], s1); s2 = fmaf(cgw[o*CG+i], m2[i], s2); }
    chg1[o] = sigmoidf_(s1); chg2[o] = sigmoidf_(s2);
  }
  float z1[CG], z2[CG];
  float mx1 = -1e30f, mx2 = -1e30f;
  #pragma unroll
  for (int c = 0; c < CG; ++c){
    z1[c] = chg1[c]*q1[c]; z2[c] = chg2[c]*q2[c];
    mx1 = fmaxf(mx1, z1[c]); mx2 = fmaxf(mx2, z2[c]);
  }
  float su1 = 0.f, su2 = 0.f;
  #pragma unroll
  for (int c = 0; c < CG; ++c){
    z1[c] = __expf(z1[c]-mx1); su1 += z1[c];
    z2[c] = __expf(z2[c]-mx2); su2 += z2[c];
  }
  float i1 = 1.0f/su1, i2 = 1.0f/su2;
  #pragma unroll
  for (int c = 0; c < CG; ++c){
    float x11 = z1[c]*i1;   // softmax of gated-x1 means
    float x21 = z2[c]*i2;   // softmax of gated-x2 means
    a1a2[n*16 + c]     = x21 * chg1[c];  // coefficient on x1 map
    a1a2[n*16 + 8 + c] = x11 * chg2[c];  // coefficient on x2 map
  }
}

// ---------------- Kernel F: final weights + output -----------------------------
__global__ __launch_bounds__(256) void kF(const float* __restrict__ gx,
                                          const unsigned short* __restrict__ x1m,
                                          const unsigned short* __restrict__ x2m,
                                          const float* __restrict__ a1a2,
                                          const float* __restrict__ spw,
                                          float* __restrict__ out){
  int tid = threadIdx.x;
  int bb = blockIdx.x;          // 16384 blocks
  int n  = bb >> 6;
  int hw = ((bb & 63) << 8) + tid;
  size_t base = (size_t)(n*CG)*HWSZ + hw;
  float a1[CG], a2[CG], sp[CG];
  #pragma unroll
  for (int c = 0; c < CG; ++c){
    a1[c] = a1a2[n*16 + c];
    a2[c] = a1a2[n*16 + 8 + c];
    sp[c] = spw[c];
  }
  float d1 = 0.f, dd1 = 0.f, d2 = 0.f, dd2 = 0.f;
  #pragma unroll
  for (int c = 0; c < CG; ++c){
    float v1 = bf2f(x1m[base + (size_t)c*HWSZ]);
    float v2 = bf2f(x2m[base + (size_t)c*HWSZ]);
    d1  = fmaf(sp[c], v1, d1);  dd1 = fmaf(a1[c], v1, dd1);
    d2  = fmaf(sp[c], v2, d2);  dd2 = fmaf(a2[c], v2, dd2);
  }
  float Wv = sigmoidf_(d1)*dd1 + sigmoidf_(d2)*dd2;
  float sW = sigmoidf_(Wv);
  #pragma unroll
  for (int c = 0; c < CG; ++c)
    out[base + (size_t)c*HWSZ] = gx[base + (size_t)c*HWSZ] * sW;
}

extern "C" void kernel_launch(void* const* d_in, const int* in_sizes, int n_in,
                              void* d_out, int out_size, void* d_ws, size_t ws_size,
                              hipStream_t stream){
  const float* x   = (const float*)d_in[0];
  const float* afw = (const float*)d_in[1];
  const float* gnw = (const float*)d_in[2];
  const float* gnb = (const float*)d_in[3];
  const float* w1  = (const float*)d_in[4];
  const float* w3  = (const float*)d_in[5];
  const float* w5  = (const float*)d_in[6];
  const float* scw = (const float*)d_in[7];
  const float* cgw = (const float*)d_in[8];
  const float* spw = (const float*)d_in[9];

  char* ws = (char*)d_ws;
  float* sig_h = (float*)(ws + 0);               // 1 MiB
  float* sig_w = (float*)(ws + 1048576);         // 1 MiB
  float* Agn   = (float*)(ws + 2097152);         // 8 KiB
  float* Bgn   = (float*)(ws + 2105344);         // 8 KiB
  float* gacc  = (float*)(ws + 2113536);         // 32 KiB
  float* a1a2  = (float*)(ws + 2146304);         // 16 KiB
  unsigned short* x1m = (unsigned short*)(ws + 2162688);            // 64 MiB
  unsigned short* x2m = (unsigned short*)(ws + 2162688 + 67108864); // 64 MiB
  float* out = (float*)d_out;

  hipMemsetAsync(gacc, 0, NN*32*sizeof(float), stream);
  kA<<<NN, 256, 0, stream>>>(x, afw, sig_h, sig_w);
  kB<<<NN*CG, 256, 0, stream>>>(x, sig_h, sig_w, gnw, gnb, Agn, Bgn);
  kC<<<NN*16, 256, 0, stream>>>(x, w1, w3, w5, scw, spw, sig_h, sig_w, Agn, Bgn, x1m, x2m, gacc);
  kT<<<4, 64, 0, stream>>>(gacc, cgw, a1a2);
  kF<<<NN*64, 256, 0, stream>>>(x, x1m, x2m, a1a2, spw, out);
}

// Round 2
// 612.174 us; speedup vs baseline: 1.1928x; 1.1928x over previous
//
#include <hip/hip_runtime.h>
#include <math.h>

#define HH 128
#define WW 128
#define CG 8
#define NN 256
#define HWSZ (HH*WW)

__device__ __forceinline__ float sigmoidf_(float x){ return 1.0f/(1.0f+__expf(-x)); }

__device__ __forceinline__ unsigned short f2bf(float x){
  union { float f; unsigned u; } v; v.f = x;
  unsigned r = v.u + 0x7fffu + ((v.u >> 16) & 1u);
  return (unsigned short)(r >> 16);
}
__device__ __forceinline__ float bf2f(unsigned short h){
  union { unsigned u; float f; } v; v.u = ((unsigned)h) << 16; return v.f;
}

// ---------------- Kernel W: pre-scale 5x5 weights by softmax(scale_w)[2] -------
__global__ void kW(const float* __restrict__ w5, const float* __restrict__ scw,
                   float* __restrict__ w5s){
  int i = blockIdx.x*256 + threadIdx.x;
  if (i >= CG*CG*25) return;
  float a = scw[0], b = scw[1], c = scw[2];
  float m = fmaxf(a, fmaxf(b, c));
  float e0 = __expf(a-m), e1 = __expf(b-m), e2 = __expf(c-m);
  float sw2 = e2 / (e0+e1+e2);
  w5s[i] = sw2 * w5[i];
}

// ---------------- Kernel A1: per-(n,c) row & column means ----------------------
__global__ __launch_bounds__(256) void kA1(const float* __restrict__ gx,
                                           float* __restrict__ xh_ws,
                                           float* __restrict__ xw_ws){
  int b = blockIdx.x; int n = b >> 3; int c = b & 7;
  int tid = threadIdx.x;
  __shared__ float colpart[2][WW];
  const float* img = gx + (size_t)(n*CG+c)*HWSZ;
  // column sums (coalesced HBM read)
  int w = tid & 127, half = tid >> 7;
  float acc = 0.f;
  const float* p = img + half*64*WW + w;
  for (int h = 0; h < 64; ++h) acc += p[h*WW];
  colpart[half][w] = acc;
  // row sums (L2-hot second read)
  int h2 = tid >> 1, wh = tid & 1;
  float racc = 0.f;
  const float* rp = img + h2*WW + wh*64;
  for (int j = 0; j < 64; ++j) racc += rp[j];
  racc += __shfl_xor(racc, 1);
  __syncthreads();
  if (tid < WW) xw_ws[(n*CG+c)*WW + tid] = (colpart[0][tid] + colpart[1][tid]) * (1.0f/HH);
  if (wh == 0) xh_ws[(n*CG+c)*HH + h2] = racc * (1.0f/WW);
}

// ---------------- Kernel A2: 8x8 fuse conv + sigmoid ---------------------------
__global__ __launch_bounds__(256) void kA2(const float* __restrict__ xh_ws,
                                           const float* __restrict__ xw_ws,
                                           const float* __restrict__ afw,
                                           float* __restrict__ sig_h,
                                           float* __restrict__ sig_w){
  int n = blockIdx.x;
  int tid = threadIdx.x;
  if (tid < HH){
    int h = tid;
    float v[CG];
    #pragma unroll
    for (int c = 0; c < CG; ++c) v[c] = xh_ws[(n*CG+c)*HH + h];
    #pragma unroll
    for (int o = 0; o < CG; ++o){
      float s = 0.f;
      #pragma unroll
      for (int i = 0; i < CG; ++i) s = fmaf(afw[o*CG+i], v[i], s);
      sig_h[(n*CG+o)*HH + h] = sigmoidf_(s);
    }
  } else {
    int w = tid - 128;
    float v[CG];
    #pragma unroll
    for (int c = 0; c < CG; ++c) v[c] = xw_ws[(n*CG+c)*WW + w];
    #pragma unroll
    for (int o = 0; o < CG; ++o){
      float s = 0.f;
      #pragma unroll
      for (int i = 0; i < CG; ++i) s = fmaf(afw[o*CG+i], v[i], s);
      sig_w[(n*CG+o)*WW + w] = sigmoidf_(s);
    }
  }
}

// ---------------- Kernel B: GroupNorm stats of t = gx*sigh*sigw ----------------
__global__ __launch_bounds__(256) void kB(const float* __restrict__ gx,
                                          const float* __restrict__ sig_h,
                                          const float* __restrict__ sig_w,
                                          const float* __restrict__ gn_w,
                                          const float* __restrict__ gn_b,
                                          float* __restrict__ Agn,
                                          float* __restrict__ Bgn){
  int b = blockIdx.x; int n = b >> 3; int c = b & 7;
  int tid = threadIdx.x;
  __shared__ float sh[HH];
  __shared__ float swv[WW];
  __shared__ float red[16];
  if (tid < HH) sh[tid] = sig_h[(n*CG+c)*HH + tid];
  else          swv[tid-128] = sig_w[(n*CG+c)*WW + tid - 128];
  __syncthreads();
  const float* img = gx + (size_t)(n*CG+c)*HWSZ;
  float s1 = 0.f, s2 = 0.f;
  for (int idx = tid; idx < HWSZ; idx += 256){
    int h = idx >> 7, w = idx & 127;
    float t = img[idx] * sh[h] * swv[w];
    s1 += t; s2 = fmaf(t, t, s2);
  }
  #pragma unroll
  for (int off = 32; off; off >>= 1){ s1 += __shfl_down(s1, off); s2 += __shfl_down(s2, off); }
  int wv = tid >> 6, ln = tid & 63;
  if (ln == 0){ red[wv] = s1; red[8+wv] = s2; }
  __syncthreads();
  if (tid == 0){
    float S1 = red[0]+red[1]+red[2]+red[3];
    float S2 = red[8]+red[9]+red[10]+red[11];
    float mu  = S1 * (1.0f/HWSZ);
    float var = S2 * (1.0f/HWSZ) - mu*mu;
    float rstd = rsqrtf(var + 1e-5f);
    float A = rstd * gn_w[c];
    Agn[n*CG+c] = A;
    Bgn[n*CG+c] = gn_b[c] - mu*A;
  }
}

// ---------------- Kernel C: fused convs, x1/x2 maps + gate partial sums --------
// Weights read from GLOBAL with wave-uniform indices -> s_load (scalar pipe).
// Tile stored bf16 in LDS (26 KB total) -> higher occupancy, fewer conflicts.
__global__ __launch_bounds__(256) void kC(const float* __restrict__ gx,
                                          const float* __restrict__ w1,
                                          const float* __restrict__ w3,
                                          const float* __restrict__ w5s,
                                          const float* __restrict__ scale_w,
                                          const float* __restrict__ spw,
                                          const float* __restrict__ sig_h,
                                          const float* __restrict__ sig_w,
                                          const float* __restrict__ Agn,
                                          const float* __restrict__ Bgn,
                                          unsigned short* __restrict__ x1m,
                                          unsigned short* __restrict__ x2m,
                                          float* __restrict__ gacc){
  __shared__ __align__(16) unsigned short tile[CG][36][40]; // bf16, 23040 B
  __shared__ float coefA[CG][CG];
  __shared__ float constA[CG];
  __shared__ float sighs[CG][32];
  __shared__ float sigws[CG][32];
  __shared__ float wred[4][32];

  int tid = threadIdx.x;
  int bb = blockIdx.x;
  int n  = bb >> 4;
  int t_ = bb & 15;
  int y0 = (t_ >> 2) * 32;
  int x0 = (t_ & 3) * 32;

  // softmax(scale_w): need sw0 (1x1 path) and sw1 (3x3 mix); sw2 folded into w5s
  float sw0, sw1;
  {
    float a = scale_w[0], b = scale_w[1], c = scale_w[2];
    float m = fmaxf(a, fmaxf(b, c));
    float e0 = __expf(a-m), e1 = __expf(b-m), e2 = __expf(c-m);
    float inv = 1.0f/(e0+e1+e2);
    sw0 = e0*inv; sw1 = e1*inv;
  }
  if (tid < 64){
    int oc = tid >> 3, ic = tid & 7;
    coefA[oc][ic] = sw0 * w1[oc*CG+ic] * Agn[n*CG+ic];
  }
  if (tid < CG){
    float s = 0.f;
    for (int i = 0; i < CG; ++i) s = fmaf(w1[tid*CG+i], Bgn[n*CG+i], s);
    constA[tid] = sw0 * s;
  }
  {
    int ic = tid >> 5, k = tid & 31;
    sighs[ic][k] = sig_h[(n*CG+ic)*HH + y0 + k];
    sigws[ic][k] = sig_w[(n*CG+ic)*WW + x0 + k];
  }
  const float* base_n = gx + (size_t)n*CG*HWSZ;
  #pragma unroll 1
  for (int ic = 0; ic < CG; ++ic){
    const float* img = base_n + ic*HWSZ;
    for (int idx = tid; idx < 36*36; idx += 256){
      int yy = idx / 36, xx = idx - yy*36;
      int gy = y0 + yy - 2, gxx = x0 + xx - 2;
      float v = 0.f;
      if (gy >= 0 && gy < HH && gxx >= 0 && gxx < WW) v = img[gy*WW + gxx];
      tile[ic][yy][xx] = f2bf(v);
    }
  }
  __syncthreads();

  int tc = tid & 7, row = tid >> 3;
  int xl = tc * 4;
  float accA[CG][4];  // constA + sw0*1x1 + (sw2-scaled) 5x5
  float accB[CG][4];  // raw 3x3 (= x2)
  #pragma unroll
  for (int oc = 0; oc < CG; ++oc){
    float c0 = constA[oc];
    #pragma unroll
    for (int p = 0; p < 4; ++p){ accA[oc][p] = c0; accB[oc][p] = 0.f; }
  }

  #pragma unroll 1
  for (int ic = 0; ic < CG; ++ic){
    float shh = sighs[ic][row];
    float sg0 = sigws[ic][xl], sg1 = sigws[ic][xl+1], sg2 = sigws[ic][xl+2], sg3 = sigws[ic][xl+3];
    const unsigned short* trow0 = &tile[ic][row][xl];
    const float* w5i = w5s + ic*25;   // + oc*200 + ky*5 (wave-uniform -> s_load)
    const float* w3i = w3  + ic*9;    // + oc*72  + (ky-1)*3
    #pragma unroll
    for (int ky = 0; ky < 5; ++ky){
      const unsigned short* tp = trow0 + ky*40;
      ushort4 ua = *reinterpret_cast<const ushort4*>(tp);
      ushort4 ub = *reinterpret_cast<const ushort4*>(tp + 4);
      float in[8] = {bf2f(ua.x), bf2f(ua.y), bf2f(ua.z), bf2f(ua.w),
                     bf2f(ub.x), bf2f(ub.y), bf2f(ub.z), bf2f(ub.w)};
      #pragma unroll
      for (int oc = 0; oc < CG; ++oc){
        const float* wrow = w5i + oc*(CG*25) + ky*5;
        #pragma unroll
        for (int kx = 0; kx < 5; ++kx){
          float wv = wrow[kx];
          #pragma unroll
          for (int p = 0; p < 4; ++p) accA[oc][p] = fmaf(wv, in[kx+p], accA[oc][p]);
        }
      }
      if (ky >= 1 && ky <= 3){
        #pragma unroll
        for (int oc = 0; oc < CG; ++oc){
          const float* wrow3 = w3i + oc*(CG*9) + (ky-1)*3;
          #pragma unroll
          for (int kx = 0; kx < 3; ++kx){
            float wv = wrow3[kx];
            #pragma unroll
            for (int p = 0; p < 4; ++p) accB[oc][p] = fmaf(wv, in[kx+p+1], accB[oc][p]);
          }
        }
      }
      if (ky == 2){
        float t0 = in[2]*shh*sg0, t1 = in[3]*shh*sg1, t2 = in[4]*shh*sg2, t3 = in[5]*shh*sg3;
        #pragma unroll
        for (int oc = 0; oc < CG; ++oc){
          float cf = coefA[oc][ic];
          accA[oc][0] = fmaf(cf, t0, accA[oc][0]);
          accA[oc][1] = fmaf(cf, t1, accA[oc][1]);
          accA[oc][2] = fmaf(cf, t2, accA[oc][2]);
          accA[oc][3] = fmaf(cf, t3, accA[oc][3]);
        }
      }
    }
  }

  // epilogue: sp-gates per pixel, bf16 stores, partial sums
  float sp1a[4], sp2a[4];
  #pragma unroll
  for (int p = 0; p < 4; ++p){
    float d1 = 0.f, d2 = 0.f;
    #pragma unroll
    for (int oc = 0; oc < CG; ++oc){
      float xb = accB[oc][p];
      float v1 = accA[oc][p] + sw1*xb;
      float spv = spw[oc];           // wave-uniform -> s_load
      d1 = fmaf(spv, v1, d1);
      d2 = fmaf(spv, xb, d2);
    }
    sp1a[p] = sigmoidf_(d1); sp2a[p] = sigmoidf_(d2);
  }
  int lane = tid & 63, wv = tid >> 6;
  size_t obase = (size_t)(n*CG)*HWSZ + (size_t)(y0+row)*WW + (x0+xl);
  #pragma unroll
  for (int oc = 0; oc < CG; ++oc){
    float s1 = 0.f, qq1 = 0.f, s2 = 0.f, qq2 = 0.f;
    ushort4 u1, u2;
    #pragma unroll
    for (int p = 0; p < 4; ++p){
      float xb = accB[oc][p];
      float v1 = accA[oc][p] + sw1*xb;
      s1 += v1; s2 += xb;
      qq1 = fmaf(v1, sp1a[p], qq1); qq2 = fmaf(xb, sp2a[p], qq2);
      ((unsigned short*)&u1)[p] = f2bf(v1);
      ((unsigned short*)&u2)[p] = f2bf(xb);
    }
    *reinterpret_cast<ushort4*>(x1m + obase + (size_t)oc*HWSZ) = u1;
    *reinterpret_cast<ushort4*>(x2m + obase + (size_t)oc*HWSZ) = u2;
    #pragma unroll
    for (int off = 32; off; off >>= 1){
      s1 += __shfl_down(s1, off); qq1 += __shfl_down(qq1, off);
      s2 += __shfl_down(s2, off); qq2 += __shfl_down(qq2, off);
    }
    if (lane == 0){ wred[wv][oc] = s1; wred[wv][8+oc] = qq1; wred[wv][16+oc] = s2; wred[wv][24+oc] = qq2; }
  }
  __syncthreads();
  if (tid < 32){
    float s = wred[0][tid] + wred[1][tid] + wred[2][tid] + wred[3][tid];
    atomicAdd(&gacc[n*32 + tid], s);
  }
}

// ---------------- Kernel T: channel gates + softmaxes -> a1,a2 -----------------
__global__ void kT(const float* __restrict__ gacc, const float* __restrict__ cgw,
                   float* __restrict__ a1a2){
  int n = blockIdx.x*blockDim.x + threadIdx.x;
  if (n >= NN) return;
  const float* g = gacc + n*32;
  float m1[CG], q1[CG], m2[CG], q2[CG];
  #pragma unroll
  for (int c = 0; c < CG; ++c){
    m1[c] = g[c]      * (1.0f/HWSZ);
    q1[c] = g[8+c]    * (1.0f/HWSZ);
    m2[c] = g[16+c]   * (1.0f/HWSZ);
    q2[c] = g[24+c]   * (1.0f/HWSZ);
  }
  float chg1[CG], chg2[CG];
  #pragma unroll
  for (int o = 0; o < CG; ++o){
    float s1 = 0.f, s2 = 0.f;
    #pragma unroll
    for (int i = 0; i < CG; ++i){ s1 = fmaf(cgw[o*CG+i], m1[i], s1); s2 = fmaf(cgw[o*CG+i], m2[i], s2); }
    chg1[o] = sigmoidf_(s1); chg2[o] = sigmoidf_(s2);
  }
  float z1[CG], z2[CG];
  float mx1 = -1e30f, mx2 = -1e30f;
  #pragma unroll
  for (int c = 0; c < CG; ++c){
    z1[c] = chg1[c]*q1[c]; z2[c] = chg2[c]*q2[c];
    mx1 = fmaxf(mx1, z1[c]); mx2 = fmaxf(mx2, z2[c]);
  }
  float su1 = 0.f, su2 = 0.f;
  #pragma unroll
  for (int c = 0; c < CG; ++c){
    z1[c] = __expf(z1[c]-mx1); su1 += z1[c];
    z2[c] = __expf(z2[c]-mx2); su2 += z2[c];
  }
  float i1 = 1.0f/su1, i2 = 1.0f/su2;
  #pragma unroll
  for (int c = 0; c < CG; ++c){
    float x11 = z1[c]*i1;
    float x21 = z2[c]*i2;
    a1a2[n*16 + c]     = x21 * chg1[c];
    a1a2[n*16 + 8 + c] = x11 * chg2[c];
  }
}

// ---------------- Kernel F: final weights + output -----------------------------
__global__ __launch_bounds__(256) void kF(const float* __restrict__ gx,
                                          const unsigned short* __restrict__ x1m,
                                          const unsigned short* __restrict__ x2m,
                                          const float* __restrict__ a1a2,
                                          const float* __restrict__ spw,
                                          float* __restrict__ out){
  int tid = threadIdx.x;
  int bb = blockIdx.x;
  int n  = bb >> 6;
  int hw = ((bb & 63) << 8) + tid;
  size_t base = (size_t)(n*CG)*HWSZ + hw;
  float a1[CG], a2[CG], sp[CG];
  #pragma unroll
  for (int c = 0; c < CG; ++c){
    a1[c] = a1a2[n*16 + c];
    a2[c] = a1a2[n*16 + 8 + c];
    sp[c] = spw[c];
  }
  float d1 = 0.f, dd1 = 0.f, d2 = 0.f, dd2 = 0.f;
  #pragma unroll
  for (int c = 0; c < CG; ++c){
    float v1 = bf2f(x1m[base + (size_t)c*HWSZ]);
    float v2 = bf2f(x2m[base + (size_t)c*HWSZ]);
    d1  = fmaf(sp[c], v1, d1);  dd1 = fmaf(a1[c], v1, dd1);
    d2  = fmaf(sp[c], v2, d2);  dd2 = fmaf(a2[c], v2, dd2);
  }
  float Wv = sigmoidf_(d1)*dd1 + sigmoidf_(d2)*dd2;
  float sW = sigmoidf_(Wv);
  #pragma unroll
  for (int c = 0; c < CG; ++c)
    out[base + (size_t)c*HWSZ] = gx[base + (size_t)c*HWSZ] * sW;
}

extern "C" void kernel_launch(void* const* d_in, const int* in_sizes, int n_in,
                              void* d_out, int out_size, void* d_ws, size_t ws_size,
                              hipStream_t stream){
  const float* x   = (const float*)d_in[0];
  const float* afw = (const float*)d_in[1];
  const float* gnw = (const float*)d_in[2];
  const float* gnb = (const float*)d_in[3];
  const float* w1  = (const float*)d_in[4];
  const float* w3  = (const float*)d_in[5];
  const float* w5  = (const float*)d_in[6];
  const float* scw = (const float*)d_in[7];
  const float* cgw = (const float*)d_in[8];
  const float* spw = (const float*)d_in[9];

  char* ws = (char*)d_ws;
  float* sig_h = (float*)(ws + 0);               // 1 MiB
  float* sig_w = (float*)(ws + 1048576);         // 1 MiB
  float* Agn   = (float*)(ws + 2097152);         // 8 KiB
  float* Bgn   = (float*)(ws + 2105344);         // 8 KiB
  float* gacc  = (float*)(ws + 2113536);         // 32 KiB
  float* a1a2  = (float*)(ws + 2146304);         // 16 KiB (aliases w5s: w5s dead before kT writes)
  float* w5s   = (float*)(ws + 2146304);         // 6.4 KiB, lives kW..kC only
  unsigned short* x1m = (unsigned short*)(ws + 2162688);            // 64 MiB
  unsigned short* x2m = (unsigned short*)(ws + 2162688 + 67108864); // 64 MiB
  float* out = (float*)d_out;
  // xh/xw staging lives in d_out (dead before kF writes it)
  float* xh_ws = (float*)d_out;                  // 1 MiB
  float* xw_ws = (float*)d_out + 262144;         // 1 MiB

  hipMemsetAsync(gacc, 0, NN*32*sizeof(float), stream);
  kW <<<7, 256, 0, stream>>>(w5, scw, w5s);
  kA1<<<NN*CG, 256, 0, stream>>>(x, xh_ws, xw_ws);
  kA2<<<NN, 256, 0, stream>>>(xh_ws, xw_ws, afw, sig_h, sig_w);
  kB <<<NN*CG, 256, 0, stream>>>(x, sig_h, sig_w, gnw, gnb, Agn, Bgn);
  kC <<<NN*16, 256, 0, stream>>>(x, w1, w3, w5s, scw, spw, sig_h, sig_w, Agn, Bgn, x1m, x2m, gacc);
  kT <<<4, 64, 0, stream>>>(gacc, cgw, a1a2);
  kF <<<NN*64, 256, 0, stream>>>(x, x1m, x2m, a1a2, spw, out);
}